// Round 3
// baseline (3417.868 us; speedup 1.0000x reference)
//
#include <hip/hip_runtime.h>

typedef unsigned short u16;
typedef short bfx8 __attribute__((ext_vector_type(8)));
typedef float fx4 __attribute__((ext_vector_type(4)));

__device__ __forceinline__ float b2f(u16 u) {
    union { unsigned u; float f; } c; c.u = ((unsigned)u) << 16; return c.f;
}
__device__ __forceinline__ u16 f2b(float f) {
    union { float f; unsigned u; } c; c.f = f;
    unsigned x = c.u;
    unsigned r = x + 0x7FFFu + ((x >> 16) & 1u);
    return (u16)(r >> 16);
}
__device__ __forceinline__ float bpk_lo(unsigned p) {
    union { unsigned u; float f; } c; c.u = p << 16; return c.f;
}
__device__ __forceinline__ float bpk_hi(unsigned p) {
    union { unsigned u; float f; } c; c.u = p & 0xFFFF0000u; return c.f;
}

// ---------------- f32 -> bf16 cast (8 elems/thread) ----------------
__global__ void k_cast(const float* __restrict__ xf, u16* __restrict__ xb, int n8) {
    int t = blockIdx.x * 256 + threadIdx.x;
    if (t >= n8) return;
    const float4* p = (const float4*)xf;
    float4 a = p[t * 2], b = p[t * 2 + 1];
    u16 o[8];
    o[0] = f2b(a.x); o[1] = f2b(a.y); o[2] = f2b(a.z); o[3] = f2b(a.w);
    o[4] = f2b(b.x); o[5] = f2b(b.y); o[6] = f2b(b.z); o[7] = f2b(b.w);
    ((uint4*)xb)[t] = *(uint4*)o;
}

// ---------------- CSR build ----------------

__global__ void k_deg(const int* __restrict__ dst, int* __restrict__ rp, int E) {
    int e = blockIdx.x * 256 + threadIdx.x;
    if (e < E) atomicAdd(&rp[dst[e]], 1);
}

#define SCAN_T 256
#define SCAN_I 8
#define SCAN_CH 2048

__global__ void k_scanA(int* __restrict__ rp, int* __restrict__ bsum, int N) {
    __shared__ int s[SCAN_T];
    int base = blockIdx.x * SCAN_CH + threadIdx.x * SCAN_I;
    int v[SCAN_I]; int tot = 0;
    for (int i = 0; i < SCAN_I; i++) {
        int idx = base + i;
        int x = (idx < N) ? rp[idx] : 0;
        v[i] = tot; tot += x;
    }
    s[threadIdx.x] = tot; __syncthreads();
    for (int off = 1; off < SCAN_T; off <<= 1) {
        int t = (threadIdx.x >= off) ? s[threadIdx.x - off] : 0;
        __syncthreads();
        s[threadIdx.x] += t;
        __syncthreads();
    }
    int excl = (threadIdx.x == 0) ? 0 : s[threadIdx.x - 1];
    if (threadIdx.x == SCAN_T - 1) bsum[blockIdx.x] = s[SCAN_T - 1];
    for (int i = 0; i < SCAN_I; i++) {
        int idx = base + i;
        if (idx < N) rp[idx] = excl + v[i];
    }
}

__global__ void k_scanB(int* __restrict__ bsum, int nb) {
    __shared__ int s[SCAN_T];
    int t = threadIdx.x;
    s[t] = (t < nb) ? bsum[t] : 0; __syncthreads();
    for (int off = 1; off < SCAN_T; off <<= 1) {
        int v = (t >= off) ? s[t - off] : 0;
        __syncthreads();
        s[t] += v;
        __syncthreads();
    }
    if (t < nb) bsum[t] = (t == 0) ? 0 : s[t - 1];
}

__global__ void k_scanC(const int* __restrict__ bsum, int* __restrict__ rp,
                        int* __restrict__ cursor, int N, int E) {
    int i = blockIdx.x * 256 + threadIdx.x;
    if (i < N) {
        int v = rp[i] + bsum[i >> 11];
        rp[i] = v; cursor[i] = v;
    } else if (i == N) {
        rp[N] = E;
    }
}

// v3: single int2 (src,eid) store per edge -- halves the number of random dirty
// lines vs two separate 4B stores (WRITE_SIZE was 382 MB for 32 MB of payload).
__global__ void k_fill(const int* __restrict__ src, const int* __restrict__ dst,
                       int* __restrict__ cursor, int2* __restrict__ col, int E) {
    int e = blockIdx.x * 256 + threadIdx.x;
    if (e >= E) return;
    int d = dst[e];
    int p = atomicAdd(&cursor[d], 1);
    col[p] = make_int2(src[e], e);
}

__global__ void k_gptr(const int* __restrict__ batch, int* __restrict__ gptr, int N, int G) {
    int g = blockIdx.x * 256 + threadIdx.x;
    if (g > G) return;
    int lo = 0, hi = N;
    while (lo < hi) { int mid = (lo + hi) >> 1; if (batch[mid] < g) lo = mid + 1; else hi = mid; }
    gptr[g] = lo;
}

// agg_e[n][m] = sum of edge_attr (f32) over in-edges of n (constant across convs)
// batch 4 eid loads then 4 independent row loads -> 4 lines in flight per chain
__global__ void k_agge(const float* __restrict__ ea, const int* __restrict__ rp,
                       const int2* __restrict__ col, float* __restrict__ agge, int N) {
    int t = blockIdx.x * 256 + threadIdx.x;
    int n = t >> 4, m = t & 15;
    if (n >= N) return;
    float v = 0.f;
    int p0 = rp[n], p1 = rp[n + 1];
    int last = p1 - 1;
    for (int p = p0; p < p1; p += 4) {
        int e[4];
#pragma unroll
        for (int k = 0; k < 4; k++) {
            int pk = p + k;
            e[k] = col[pk < p1 ? pk : last].y;   // clamp: dup line, L1-hit
        }
        float w[4];
#pragma unroll
        for (int k = 0; k < 4; k++) w[k] = ea[(size_t)e[k] * 16 + m];
#pragma unroll
        for (int k = 0; k < 4; k++) v += (p + k < p1) ? w[k] : 0.f;
    }
    agge[(size_t)n * 16 + m] = v;
}

// ---------------- fused softmax + segment-sum pool (block-cooperative, single MFMA pass) --------
// v3: one 1024-thread block owns a 32-node tile. 16 waves each compute a 32-feature
// slice ONCE (B-fragments in registers, no W LDS), store exp(z) to a shared LDS
// buffer (stride 516 f32 to break bank conflicts), cross-reduce denominators in LDS,
// then a feature-parallel phase accumulates exp*rinv into registers with a coalesced
// 2KB fp write per graph. Halves MFMA + exp work vs the old two-phase recompute.
// Next-tile A-fragments are prefetched under phases B/C.
#define EXP_STRIDE 516
__global__ __launch_bounds__(1024) void k_pass(
    const u16* __restrict__ x, const float* __restrict__ Wow, const float* __restrict__ Wob,
    const int* __restrict__ gptr, float* __restrict__ fp, int G, int writeMode)
{
    __shared__ float expL[32 * EXP_STRIDE];   // 66 KB  [row][feat] padded
    __shared__ float rinvL[32];
    __shared__ float combL[512];

    const int tid = threadIdx.x;
    const int wid = tid >> 6, lane = tid & 63;
    const int quad = lane >> 4, col = lane & 15;
    const int ft0 = wid * 2, ft1 = ft0 + 1;

    // B fragments in registers: B[0],B[1] = ft0 k-halves; B[2],B[3] = ft1 k-halves
    bfx8 B[4];
#pragma unroll
    for (int i = 0; i < 4; i++) {
        int ft = (i >> 1) ? ft1 : ft0, kt = i & 1;
        int f = ft * 16 + col;
        int k = kt * 32 + quad * 8;
        const float* wp = Wow + f * 64 + k;
        u16 o[8];
#pragma unroll
        for (int j = 0; j < 8; j++) o[j] = f2b(wp[j]);
        B[i] = *(bfx8*)o;
    }
    const float bias0 = Wob[ft0 * 16 + col], bias1 = Wob[ft1 * 16 + col];

    const int fC = tid & 511, hC = tid >> 9;   // phase-C mapping (feat, half)
    const int tn = tid >> 5, tc = tid & 31;    // phase-B mapping (node, chunk)

    for (int g = blockIdx.x; g < G; g += gridDim.x) {
        const int gs = gptr[g], ge = gptr[g + 1];
        float fpacc = 0.f;

        uint4 f0, f1, f2, f3;
        {   // preload first tile
            int b = gs;
            if (b < ge) {
                int n0 = b + col, n1 = n0 + 16;
                const uint4* r0 = (const uint4*)(x + (size_t)((n0 < ge) ? n0 : gs) * 64);
                const uint4* r1 = (const uint4*)(x + (size_t)((n1 < ge) ? n1 : gs) * 64);
                f0 = r0[quad]; f1 = r0[quad + 4]; f2 = r1[quad]; f3 = r1[quad + 4];
            }
        }

        for (int base = gs; base < ge; base += 32) {
            int rows = ge - base; if (rows > 32) rows = 32;
            bfx8 a0 = *(bfx8*)&f0, a1 = *(bfx8*)&f1, a2 = *(bfx8*)&f2, a3 = *(bfx8*)&f3;
            // prefetch next tile under phases B/C
            if (base + 32 < ge) {
                int b = base + 32;
                int n0 = b + col, n1 = n0 + 16;
                const uint4* r0 = (const uint4*)(x + (size_t)((n0 < ge) ? n0 : gs) * 64);
                const uint4* r1 = (const uint4*)(x + (size_t)((n1 < ge) ? n1 : gs) * 64);
                f0 = r0[quad]; f1 = r0[quad + 4]; f2 = r1[quad]; f3 = r1[quad + 4];
            }
            // phase A: z = x@W.T + b for my 2 feature-slices, exp -> LDS
            fx4 c00 = {bias0, bias0, bias0, bias0}, c01 = c00;
            fx4 c10 = {bias1, bias1, bias1, bias1}, c11 = c10;
            c00 = __builtin_amdgcn_mfma_f32_16x16x32_bf16(a0, B[0], c00, 0, 0, 0);
            c00 = __builtin_amdgcn_mfma_f32_16x16x32_bf16(a1, B[1], c00, 0, 0, 0);
            c01 = __builtin_amdgcn_mfma_f32_16x16x32_bf16(a2, B[0], c01, 0, 0, 0);
            c01 = __builtin_amdgcn_mfma_f32_16x16x32_bf16(a3, B[1], c01, 0, 0, 0);
            c10 = __builtin_amdgcn_mfma_f32_16x16x32_bf16(a0, B[2], c10, 0, 0, 0);
            c10 = __builtin_amdgcn_mfma_f32_16x16x32_bf16(a1, B[3], c10, 0, 0, 0);
            c11 = __builtin_amdgcn_mfma_f32_16x16x32_bf16(a2, B[2], c11, 0, 0, 0);
            c11 = __builtin_amdgcn_mfma_f32_16x16x32_bf16(a3, B[3], c11, 0, 0, 0);
#pragma unroll
            for (int r = 0; r < 4; r++) {
                int row0 = quad * 4 + r;
                expL[row0 * EXP_STRIDE + ft0 * 16 + col]        = __expf(c00[r]);
                expL[(row0 + 16) * EXP_STRIDE + ft0 * 16 + col] = __expf(c01[r]);
                expL[row0 * EXP_STRIDE + ft1 * 16 + col]        = __expf(c10[r]);
                expL[(row0 + 16) * EXP_STRIDE + ft1 * 16 + col] = __expf(c11[r]);
            }
            __syncthreads();
            // phase B: per-node denominator (32 threads per node, 16 feats each)
            float part = 0.f;
            int rb = tn * EXP_STRIDE + tc;
#pragma unroll
            for (int j = 0; j < 16; j++) part += expL[rb + j * 32];
#pragma unroll
            for (int off = 1; off < 32; off <<= 1) part += __shfl_xor(part, off, 64);
            if (tc == 0) rinvL[tn] = (tn < rows) ? __builtin_amdgcn_rcpf(part) : 0.f;
            __syncthreads();
            // phase C: fp[feat] += sum_n exp[n][feat] * rinv[n]
            for (int n = hC; n < rows; n += 2)
                fpacc += expL[n * EXP_STRIDE + fC] * rinvL[n];
            __syncthreads();
        }
        // combine halves + coalesced write
        if (hC == 1) combL[fC] = fpacc;
        __syncthreads();
        if (hC == 0) {
            float v = fpacc + combL[fC];
            float* dp = fp + (size_t)g * 512 + fC;
            if (writeMode) *dp = v; else *dp += v;
        }
        __syncthreads();
    }
}

// ---------------- conv part 1: y = x @ W1.T (MFMA, N x 64 x 64) ----------------
__global__ __launch_bounds__(256) void k_gemm(
    const u16* __restrict__ x, const float* __restrict__ Wiw, u16* __restrict__ y, int N)
{
    __shared__ u16 Wsw[8 * 64 * 8];
    for (int s = threadIdx.x; s < 512; s += 256) {
        int frag = s >> 6, lane = s & 63;
        int ft = frag >> 1, kt = frag & 1;
        int f = ft * 16 + (lane & 15);
        int k = kt * 32 + ((lane >> 4) & 3) * 8;
        const float* wp = Wiw + f * 80 + k;      // W1[f][k] = W_in_w[f*80 + k]
        u16 o[8];
#pragma unroll
        for (int i = 0; i < 8; i++) o[i] = f2b(wp[i]);
        ((uint4*)Wsw)[s] = *(uint4*)o;
    }
    __syncthreads();
    const int wid = threadIdx.x >> 6, lane = threadIdx.x & 63;
    const int quad = lane >> 4, col = lane & 15;
    int ntile = N >> 4;
    for (int t = blockIdx.x * 4 + wid; t < ntile; t += gridDim.x * 4) {
        const uint4* rowp = (const uint4*)(x + (size_t)(t * 16 + col) * 64);
        uint4 a0u = rowp[quad], a1u = rowp[quad + 4];
        bfx8 a0 = *(bfx8*)&a0u, a1 = *(bfx8*)&a1u;
#pragma unroll
        for (int ft = 0; ft < 4; ft++) {
            fx4 acc = {0.f, 0.f, 0.f, 0.f};
            bfx8 b0 = *(bfx8*)(Wsw + ((ft * 2 + 0) * 64 + lane) * 8);
            bfx8 b1 = *(bfx8*)(Wsw + ((ft * 2 + 1) * 64 + lane) * 8);
            acc = __builtin_amdgcn_mfma_f32_16x16x32_bf16(a0, b0, acc, 0, 0, 0);
            acc = __builtin_amdgcn_mfma_f32_16x16x32_bf16(a1, b1, acc, 0, 0, 0);
#pragma unroll
            for (int r = 0; r < 4; r++)
                y[(size_t)(t * 16 + quad * 4 + r) * 64 + ft * 16 + col] = f2b(acc[r]);
        }
    }
}

// ---------------- conv part 2: x_out[n] = y[n] + sum_{e->n} y[src] + agg_e[n]@W2.T + b --------
// 2 nodes/wave (32 lanes x bf16-pair each -> dword row loads) + chunk-8 batched
// index / row loads => up to 16 cache lines in flight per wave.
__global__ __launch_bounds__(256) void k_gath(
    const u16* __restrict__ y, const float* __restrict__ agge,
    const float* __restrict__ Wiw, const float* __restrict__ Wib,
    const int* __restrict__ rp, const int2* __restrict__ col,
    u16* __restrict__ xb, int N)
{
    __shared__ float W2t[16 * 64];
    __shared__ float bias[64];
    for (int s = threadIdx.x; s < 1024; s += 256) {
        int m = s >> 6, j = s & 63;
        W2t[s] = Wiw[j * 80 + 64 + m];
    }
    if (threadIdx.x < 64) bias[threadIdx.x] = Wib[threadIdx.x];
    __syncthreads();
    const int wid = threadIdx.x >> 6, lane = threadIdx.x & 63;
    const int half = lane >> 5, f = lane & 31;     // this lane owns features 2f, 2f+1
    const int P = (N + 1) >> 1;                    // node pairs
    const int nw = gridDim.x * 4;
    for (int i = blockIdx.x * 4 + wid; i < P; i += nw) {
        int n = i * 2 + half;
        bool valid = n < N;
        int nn = valid ? n : (N - 1);
        // self loop + bias
        unsigned su = *(const unsigned*)(y + (size_t)nn * 64 + 2 * f);
        float ax = bpk_lo(su) + bias[2 * f];
        float ay = bpk_hi(su) + bias[2 * f + 1];
        int p0 = rp[nn], p1 = rp[nn + 1];
        int last = p1 - 1;
        for (int p = p0; p < p1; p += 8) {
            int s[8];
#pragma unroll
            for (int k = 0; k < 8; k++) {
                int pk = p + k;
                s[k] = col[pk < p1 ? pk : last].x;   // clamp: dup line, L1-hit
            }
            unsigned u[8];
#pragma unroll
            for (int k = 0; k < 8; k++)
                u[k] = *(const unsigned*)(y + (size_t)s[k] * 64 + 2 * f);
            float sx = 0.f, sy = 0.f;
#pragma unroll
            for (int k = 0; k < 8; k++) {
                bool ok = (p + k) < p1;
                sx += ok ? bpk_lo(u[k]) : 0.f;
                sy += ok ? bpk_hi(u[k]) : 0.f;
            }
            ax += sx; ay += sy;
        }
        // + agg_e @ W2.T
        const float4* aev = (const float4*)(agge + (size_t)nn * 16);
#pragma unroll
        for (int q = 0; q < 4; q++) {
            float4 a4 = aev[q];
            int m0 = q * 4;
            ax += a4.x * W2t[(m0 + 0) * 64 + 2 * f] + a4.y * W2t[(m0 + 1) * 64 + 2 * f]
                + a4.z * W2t[(m0 + 2) * 64 + 2 * f] + a4.w * W2t[(m0 + 3) * 64 + 2 * f];
            ay += a4.x * W2t[(m0 + 0) * 64 + 2 * f + 1] + a4.y * W2t[(m0 + 1) * 64 + 2 * f + 1]
                + a4.z * W2t[(m0 + 2) * 64 + 2 * f + 1] + a4.w * W2t[(m0 + 3) * 64 + 2 * f + 1];
        }
        if (valid) {
            unsigned o = ((unsigned)f2b(ax)) | (((unsigned)f2b(ay)) << 16);
            *(unsigned*)(xb + (size_t)n * 64 + 2 * f) = o;
        }
    }
}

// ---------------- head: sigmoid(lin2(lin1(fp))) — all f32 ----------------
__global__ __launch_bounds__(256) void k_head(
    const float* __restrict__ fp, const float* __restrict__ l1w, const float* __restrict__ l1b,
    const float* __restrict__ l2w, const float* __restrict__ l2b, float* __restrict__ out, int G)
{
    const int wid = threadIdx.x >> 6, lane = threadIdx.x & 63;
    int g = blockIdx.x * 4 + wid;
    if (g >= G) return;
    int j = lane < 50 ? lane : 49;
    float h = 0.f;
    const float4* fv = (const float4*)(fp + (size_t)g * 512);
    const float4* wv = (const float4*)(l1w + (size_t)j * 512);
    for (int q = 0; q < 128; q++) {
        float4 w = wv[q], f = fv[q];
        h += w.x * f.x + w.y * f.y + w.z * f.z + w.w * f.w;
    }
    h += l1b[j];
    float val = (lane < 50) ? h * l2w[lane] : 0.f;
#pragma unroll
    for (int off = 1; off < 64; off <<= 1) val += __shfl_xor(val, off, 64);
    if (lane == 0) {
        float o = val + l2b[0];
        out[g] = 1.f / (1.f + __expf(-o));
    }
}

extern "C" void kernel_launch(void* const* d_in, const int* in_sizes, int n_in,
                              void* d_out, int out_size, void* d_ws, size_t ws_size,
                              hipStream_t stream)
{
    const float* x    = (const float*)d_in[0];
    const float* ea   = (const float*)d_in[1];
    const float* Wiw  = (const float*)d_in[2];
    const float* Wib  = (const float*)d_in[3];
    const float* Wow  = (const float*)d_in[4];
    const float* Wob  = (const float*)d_in[5];
    const float* l1w  = (const float*)d_in[6];
    const float* l1b  = (const float*)d_in[7];
    const float* l2w  = (const float*)d_in[8];
    const float* l2b  = (const float*)d_in[9];
    const int* ei     = (const int*)d_in[10];
    const int* batch  = (const int*)d_in[11];
    float* out = (float*)d_out;

    const int N = in_sizes[0] / 64;
    const int E = in_sizes[10] / 2;
    const int G = 16384;
    const int* src = ei;
    const int* dst = ei + E;

    size_t o = 0;
    auto give = [&](size_t bytes) {
        char* p = (char*)d_ws + o;
        o += (bytes + 255) & ~(size_t)255;
        return (void*)p;
    };
    u16*   x16     = (u16*)  give((size_t)N * 64 * 2);   // bf16 cast of input x
    u16*   xb      = (u16*)  give((size_t)N * 64 * 2);   // conv output (bf16)
    u16*   y       = (u16*)  give((size_t)N * 64 * 2);   // x @ W1.T  (bf16)
    float* agge    = (float*)give((size_t)N * 16 * 4);
    float* fp      = (float*)give((size_t)G * 512 * 4);
    int*   rp      = (int*)  give((size_t)(N + 1) * 4);
    int*   cursor  = (int*)  give((size_t)N * 4);
    int2*  col     = (int2*) give((size_t)E * 8);        // packed (src, eid)
    int*   bsum    = (int*)  give(4096);
    int*   gptr    = (int*)  give((size_t)(G + 1) * 4);

    // CSR build (inputs identical each call so result identical each launch)
    hipMemsetAsync(rp, 0, (size_t)(N + 1) * 4, stream);
    k_deg<<<(E + 255) / 256, 256, 0, stream>>>(dst, rp, E);
    int nb = (N + SCAN_CH - 1) / SCAN_CH;       // 245 for N=500000 (must be <= 256)
    k_scanA<<<nb, SCAN_T, 0, stream>>>(rp, bsum, N);
    k_scanB<<<1, SCAN_T, 0, stream>>>(bsum, nb);
    k_scanC<<<(N + 256) / 256, 256, 0, stream>>>(bsum, rp, cursor, N, E);
    k_fill<<<(E + 255) / 256, 256, 0, stream>>>(src, dst, cursor, col, E);
    k_gptr<<<(G + 256) / 256, 256, 0, stream>>>(batch, gptr, N, G);
    k_agge<<<(N * 16 + 255) / 256, 256, 0, stream>>>(ea, rp, col, agge, N);

    // cast input x -> bf16
    k_cast<<<(N * 64 / 8 + 255) / 256, 256, 0, stream>>>(x, x16, N * 64 / 8);

    // pass 0 on input x (writes fp)
    k_pass<<<512, 1024, 0, stream>>>(x16, Wow, Wob, gptr, fp, G, 1);
    const u16* xc = x16;
    for (int d = 0; d < 4; d++) {
        k_gemm<<<1024, 256, 0, stream>>>(xc, Wiw, y, N);
        k_gath<<<2048, 256, 0, stream>>>(y, agge, Wiw, Wib, rp, col, xb, N);
        xc = xb;
        k_pass<<<512, 1024, 0, stream>>>(xc, Wow, Wob, gptr, fp, G, 0);
    }
    k_head<<<G / 4, 256, 0, stream>>>(fp, l1w, l1b, l2w, l2b, out, G);
}

// Round 4
// 2911.504 us; speedup vs baseline: 1.1739x; 1.1739x over previous
//
#include <hip/hip_runtime.h>

typedef unsigned short u16;
typedef short bfx8 __attribute__((ext_vector_type(8)));
typedef float fx4 __attribute__((ext_vector_type(4)));

__device__ __forceinline__ float b2f(u16 u) {
    union { unsigned u; float f; } c; c.u = ((unsigned)u) << 16; return c.f;
}
__device__ __forceinline__ u16 f2b(float f) {
    union { float f; unsigned u; } c; c.f = f;
    unsigned x = c.u;
    unsigned r = x + 0x7FFFu + ((x >> 16) & 1u);
    return (u16)(r >> 16);
}
__device__ __forceinline__ float bpk_lo(unsigned p) {
    union { unsigned u; float f; } c; c.u = p << 16; return c.f;
}
__device__ __forceinline__ float bpk_hi(unsigned p) {
    union { unsigned u; float f; } c; c.u = p & 0xFFFF0000u; return c.f;
}
// pack two f32 into one reg of 2x bf16 (RNE) -- single VALU instr
__device__ __forceinline__ unsigned cvtpk(float lo, float hi) {
    unsigned r;
    asm("v_cvt_pk_bf16_f32 %0, %1, %2" : "=v"(r) : "v"(lo), "v"(hi));
    return r;
}

// ---------------- f32 -> bf16 cast (8 elems/thread) ----------------
__global__ void k_cast(const float* __restrict__ xf, u16* __restrict__ xb, int n8) {
    int t = blockIdx.x * 256 + threadIdx.x;
    if (t >= n8) return;
    const float4* p = (const float4*)xf;
    float4 a = p[t * 2], b = p[t * 2 + 1];
    u16 o[8];
    o[0] = f2b(a.x); o[1] = f2b(a.y); o[2] = f2b(a.z); o[3] = f2b(a.w);
    o[4] = f2b(b.x); o[5] = f2b(b.y); o[6] = f2b(b.z); o[7] = f2b(b.w);
    ((uint4*)xb)[t] = *(uint4*)o;
}

// ---------------- CSR build ----------------

__global__ void k_deg(const int* __restrict__ dst, int* __restrict__ rp, int E) {
    int e = blockIdx.x * 256 + threadIdx.x;
    if (e < E) atomicAdd(&rp[dst[e]], 1);
}

#define SCAN_T 256
#define SCAN_I 8
#define SCAN_CH 2048

__global__ void k_scanA(int* __restrict__ rp, int* __restrict__ bsum, int N) {
    __shared__ int s[SCAN_T];
    int base = blockIdx.x * SCAN_CH + threadIdx.x * SCAN_I;
    int v[SCAN_I]; int tot = 0;
    for (int i = 0; i < SCAN_I; i++) {
        int idx = base + i;
        int x = (idx < N) ? rp[idx] : 0;
        v[i] = tot; tot += x;
    }
    s[threadIdx.x] = tot; __syncthreads();
    for (int off = 1; off < SCAN_T; off <<= 1) {
        int t = (threadIdx.x >= off) ? s[threadIdx.x - off] : 0;
        __syncthreads();
        s[threadIdx.x] += t;
        __syncthreads();
    }
    int excl = (threadIdx.x == 0) ? 0 : s[threadIdx.x - 1];
    if (threadIdx.x == SCAN_T - 1) bsum[blockIdx.x] = s[SCAN_T - 1];
    for (int i = 0; i < SCAN_I; i++) {
        int idx = base + i;
        if (idx < N) rp[idx] = excl + v[i];
    }
}

__global__ void k_scanB(int* __restrict__ bsum, int nb) {
    __shared__ int s[SCAN_T];
    int t = threadIdx.x;
    s[t] = (t < nb) ? bsum[t] : 0; __syncthreads();
    for (int off = 1; off < SCAN_T; off <<= 1) {
        int v = (t >= off) ? s[t - off] : 0;
        __syncthreads();
        s[t] += v;
        __syncthreads();
    }
    if (t < nb) bsum[t] = (t == 0) ? 0 : s[t - 1];
}

__global__ void k_scanC(const int* __restrict__ bsum, int* __restrict__ rp,
                        int* __restrict__ cursor, int N, int E) {
    int i = blockIdx.x * 256 + threadIdx.x;
    if (i < N) {
        int v = rp[i] + bsum[i >> 11];
        rp[i] = v; cursor[i] = v;
    } else if (i == N) {
        rp[N] = E;
    }
}

// single int2 (src,eid) store per edge
__global__ void k_fill(const int* __restrict__ src, const int* __restrict__ dst,
                       int* __restrict__ cursor, int2* __restrict__ col, int E) {
    int e = blockIdx.x * 256 + threadIdx.x;
    if (e >= E) return;
    int d = dst[e];
    int p = atomicAdd(&cursor[d], 1);
    col[p] = make_int2(src[e], e);
}

__global__ void k_gptr(const int* __restrict__ batch, int* __restrict__ gptr, int N, int G) {
    int g = blockIdx.x * 256 + threadIdx.x;
    if (g > G) return;
    int lo = 0, hi = N;
    while (lo < hi) { int mid = (lo + hi) >> 1; if (batch[mid] < g) lo = mid + 1; else hi = mid; }
    gptr[g] = lo;
}

// agg_e[n][m] = sum of edge_attr (f32) over in-edges of n (constant across convs)
__global__ void k_agge(const float* __restrict__ ea, const int* __restrict__ rp,
                       const int2* __restrict__ col, float* __restrict__ agge, int N) {
    int t = blockIdx.x * 256 + threadIdx.x;
    int n = t >> 4, m = t & 15;
    if (n >= N) return;
    float v = 0.f;
    int p0 = rp[n], p1 = rp[n + 1];
    int last = p1 - 1;
    for (int p = p0; p < p1; p += 4) {
        int e[4];
#pragma unroll
        for (int k = 0; k < 4; k++) {
            int pk = p + k;
            e[k] = col[pk < p1 ? pk : last].y;   // clamp: dup line, L1-hit
        }
        float w[4];
#pragma unroll
        for (int k = 0; k < 4; k++) w[k] = ea[(size_t)e[k] * 16 + m];
#pragma unroll
        for (int k = 0; k < 4; k++) v += (p + k < p1) ? w[k] : 0.f;
    }
    agge[(size_t)n * 16 + m] = v;
}

// ---------------- fused softmax + segment-sum pool (wave-autonomous, single MFMA+exp pass) ------
// v4: each wave owns a graph (no block barriers in the main loop -> latency hiding
// across 4 waves/block x 2 blocks/CU). Per 32-node tile: ONE MFMA+exp pass; exp(z)
// is kept in registers packed as bf16 (v_cvt_pk_bf16_f32; bf16 = truncated f32 so
// no overflow, 2^-9 rel err << existing bf16-input noise). Denominators via 16-lane
// shfl reduce; phase 2 unpacks and accumulates exp*rinv into fpacc registers.
// Halves MFMA, exp, and W-LDS traffic vs the two-phase recompute (v1/v2).
__global__ __launch_bounds__(256, 2) void k_pass(
    const u16* __restrict__ x, const float* __restrict__ Wow, const float* __restrict__ Wob,
    const int* __restrict__ gptr, float* __restrict__ fp, int G, int writeMode)
{
    __shared__ u16 Wsw[64 * 64 * 8];   // [64 frags][64 lanes][8 bf16] = 64 KB
    __shared__ float biasL[512];
    for (int s = threadIdx.x; s < 4096; s += 256) {
        int frag = s >> 6, lane = s & 63;
        int ft = frag >> 1, kt = frag & 1;
        int f = ft * 16 + (lane & 15);
        int k = kt * 32 + ((lane >> 4) & 3) * 8;
        const float* wp = Wow + f * 64 + k;      // B[k][f] = W_out[f][k], 8 consecutive k
        u16 o[8];
#pragma unroll
        for (int i = 0; i < 8; i++) o[i] = f2b(wp[i]);
        ((uint4*)Wsw)[s] = *(uint4*)o;
    }
    for (int s = threadIdx.x; s < 512; s += 256) biasL[s] = Wob[s];
    __syncthreads();
    const int wid = threadIdx.x >> 6, lane = threadIdx.x & 63;
    const int quad = lane >> 4, col = lane & 15;

    for (int g = blockIdx.x * 4 + wid; g < G; g += gridDim.x * 4) {
        const int gs = gptr[g], ge = gptr[g + 1];
        const int cnt = ge - gs;
        float fpacc[32];
#pragma unroll
        for (int t = 0; t < 32; t++) fpacc[t] = 0.f;

        uint4 p0, p1, p2, p3;
        if (gs < ge) {   // preload first tile (rows clamped to gs; garbage killed by rinv=0)
            int n0 = gs + col, n1 = n0 + 16;
            const uint4* r0 = (const uint4*)(x + (size_t)((n0 < ge) ? n0 : gs) * 64);
            const uint4* r1 = (const uint4*)(x + (size_t)((n1 < ge) ? n1 : gs) * 64);
            p0 = r0[quad]; p1 = r0[quad + 4]; p2 = r1[quad]; p3 = r1[quad + 4];
        }

        for (int base = gs; base < ge; base += 32) {
            bfx8 a0 = *(bfx8*)&p0, a1 = *(bfx8*)&p1, a2 = *(bfx8*)&p2, a3 = *(bfx8*)&p3;
            if (base + 32 < ge) {   // prefetch next tile under this tile's compute
                int b = base + 32;
                int n0 = b + col, n1 = n0 + 16;
                const uint4* r0 = (const uint4*)(x + (size_t)((n0 < ge) ? n0 : gs) * 64);
                const uint4* r1 = (const uint4*)(x + (size_t)((n1 < ge) ? n1 : gs) * 64);
                p0 = r0[quad]; p1 = r0[quad + 4]; p2 = r1[quad]; p3 = r1[quad + 4];
            }

            // phase 1: z = x@W.T + b, e = exp(z) -> packed bf16 regs, s += e
            unsigned epk[128];
            float s0[4] = {0.f, 0.f, 0.f, 0.f}, s1[4] = {0.f, 0.f, 0.f, 0.f};
#pragma unroll
            for (int ft = 0; ft < 32; ft++) {
                float b = biasL[ft * 16 + col];
                bfx8 b0 = *(bfx8*)(Wsw + ((ft * 2 + 0) * 64 + lane) * 8);
                bfx8 b1 = *(bfx8*)(Wsw + ((ft * 2 + 1) * 64 + lane) * 8);
                fx4 acc0 = {b, b, b, b}, acc1 = {b, b, b, b};
                acc0 = __builtin_amdgcn_mfma_f32_16x16x32_bf16(a0, b0, acc0, 0, 0, 0);
                acc0 = __builtin_amdgcn_mfma_f32_16x16x32_bf16(a1, b1, acc0, 0, 0, 0);
                acc1 = __builtin_amdgcn_mfma_f32_16x16x32_bf16(a2, b0, acc1, 0, 0, 0);
                acc1 = __builtin_amdgcn_mfma_f32_16x16x32_bf16(a3, b1, acc1, 0, 0, 0);
                float e00 = __expf(acc0[0]), e01 = __expf(acc0[1]);
                float e02 = __expf(acc0[2]), e03 = __expf(acc0[3]);
                float e10 = __expf(acc1[0]), e11 = __expf(acc1[1]);
                float e12 = __expf(acc1[2]), e13 = __expf(acc1[3]);
                s0[0] += e00; s0[1] += e01; s0[2] += e02; s0[3] += e03;
                s1[0] += e10; s1[1] += e11; s1[2] += e12; s1[3] += e13;
                epk[ft * 4 + 0] = cvtpk(e00, e01);
                epk[ft * 4 + 1] = cvtpk(e02, e03);
                epk[ft * 4 + 2] = cvtpk(e10, e11);
                epk[ft * 4 + 3] = cvtpk(e12, e13);
            }
            // denominators: reduce over the 16 col-lanes (each holds 32 of 512 feats)
            float rinv0[4], rinv1[4];
#pragma unroll
            for (int r = 0; r < 4; r++) {
                float t0 = s0[r], t1 = s1[r];
#pragma unroll
                for (int off = 1; off < 16; off <<= 1) {
                    t0 += __shfl_xor(t0, off, 64);
                    t1 += __shfl_xor(t1, off, 64);
                }
                int row0 = base - gs + quad * 4 + r;
                rinv0[r] = (row0 < cnt) ? __builtin_amdgcn_rcpf(t0) : 0.f;
                rinv1[r] = (row0 + 16 < cnt) ? __builtin_amdgcn_rcpf(t1) : 0.f;
            }
            // phase 2: fpacc[ft] += sum_rows e * rinv   (unpack bf16, 8 FMA/ft)
#pragma unroll
            for (int ft = 0; ft < 32; ft++) {
                float add =
                      bpk_lo(epk[ft * 4 + 0]) * rinv0[0] + bpk_hi(epk[ft * 4 + 0]) * rinv0[1]
                    + bpk_lo(epk[ft * 4 + 1]) * rinv0[2] + bpk_hi(epk[ft * 4 + 1]) * rinv0[3]
                    + bpk_lo(epk[ft * 4 + 2]) * rinv1[0] + bpk_hi(epk[ft * 4 + 2]) * rinv1[1]
                    + bpk_lo(epk[ft * 4 + 3]) * rinv1[2] + bpk_hi(epk[ft * 4 + 3]) * rinv1[3];
                fpacc[ft] += add;
            }
        }
        // cross-quad reduce + write
#pragma unroll
        for (int ft = 0; ft < 32; ft++) {
            float v = fpacc[ft];
            v += __shfl_xor(v, 16, 64);
            v += __shfl_xor(v, 32, 64);
            if (lane < 16) {
                float* dp = fp + (size_t)g * 512 + ft * 16 + col;
                if (writeMode) *dp = v; else *dp += v;
            }
        }
    }
}

// ---------------- conv part 1: y = x @ W1.T (MFMA, N x 64 x 64) ----------------
__global__ __launch_bounds__(256) void k_gemm(
    const u16* __restrict__ x, const float* __restrict__ Wiw, u16* __restrict__ y, int N)
{
    __shared__ u16 Wsw[8 * 64 * 8];
    for (int s = threadIdx.x; s < 512; s += 256) {
        int frag = s >> 6, lane = s & 63;
        int ft = frag >> 1, kt = frag & 1;
        int f = ft * 16 + (lane & 15);
        int k = kt * 32 + ((lane >> 4) & 3) * 8;
        const float* wp = Wiw + f * 80 + k;      // W1[f][k] = W_in_w[f*80 + k]
        u16 o[8];
#pragma unroll
        for (int i = 0; i < 8; i++) o[i] = f2b(wp[i]);
        ((uint4*)Wsw)[s] = *(uint4*)o;
    }
    __syncthreads();
    const int wid = threadIdx.x >> 6, lane = threadIdx.x & 63;
    const int quad = lane >> 4, col = lane & 15;
    int ntile = N >> 4;
    for (int t = blockIdx.x * 4 + wid; t < ntile; t += gridDim.x * 4) {
        const uint4* rowp = (const uint4*)(x + (size_t)(t * 16 + col) * 64);
        uint4 a0u = rowp[quad], a1u = rowp[quad + 4];
        bfx8 a0 = *(bfx8*)&a0u, a1 = *(bfx8*)&a1u;
#pragma unroll
        for (int ft = 0; ft < 4; ft++) {
            fx4 acc = {0.f, 0.f, 0.f, 0.f};
            bfx8 b0 = *(bfx8*)(Wsw + ((ft * 2 + 0) * 64 + lane) * 8);
            bfx8 b1 = *(bfx8*)(Wsw + ((ft * 2 + 1) * 64 + lane) * 8);
            acc = __builtin_amdgcn_mfma_f32_16x16x32_bf16(a0, b0, acc, 0, 0, 0);
            acc = __builtin_amdgcn_mfma_f32_16x16x32_bf16(a1, b1, acc, 0, 0, 0);
#pragma unroll
            for (int r = 0; r < 4; r++)
                y[(size_t)(t * 16 + quad * 4 + r) * 64 + ft * 16 + col] = f2b(acc[r]);
        }
    }
}

// ---------------- conv part 2: x_out[n] = y[n] + sum_{e->n} y[src] + agg_e[n]@W2.T + b --------
// 2 nodes/wave (32 lanes x bf16-pair each -> dword row loads) + chunk-8 batched
// index / row loads => up to 16 cache lines in flight per wave.
__global__ __launch_bounds__(256) void k_gath(
    const u16* __restrict__ y, const float* __restrict__ agge,
    const float* __restrict__ Wiw, const float* __restrict__ Wib,
    const int* __restrict__ rp, const int2* __restrict__ col,
    u16* __restrict__ xb, int N)
{
    __shared__ float W2t[16 * 64];
    __shared__ float bias[64];
    for (int s = threadIdx.x; s < 1024; s += 256) {
        int m = s >> 6, j = s & 63;
        W2t[s] = Wiw[j * 80 + 64 + m];
    }
    if (threadIdx.x < 64) bias[threadIdx.x] = Wib[threadIdx.x];
    __syncthreads();
    const int wid = threadIdx.x >> 6, lane = threadIdx.x & 63;
    const int half = lane >> 5, f = lane & 31;     // this lane owns features 2f, 2f+1
    const int P = (N + 1) >> 1;                    // node pairs
    const int nw = gridDim.x * 4;
    for (int i = blockIdx.x * 4 + wid; i < P; i += nw) {
        int n = i * 2 + half;
        bool valid = n < N;
        int nn = valid ? n : (N - 1);
        // self loop + bias
        unsigned su = *(const unsigned*)(y + (size_t)nn * 64 + 2 * f);
        float ax = bpk_lo(su) + bias[2 * f];
        float ay = bpk_hi(su) + bias[2 * f + 1];
        int p0 = rp[nn], p1 = rp[nn + 1];
        int last = p1 - 1;
        for (int p = p0; p < p1; p += 8) {
            int s[8];
#pragma unroll
            for (int k = 0; k < 8; k++) {
                int pk = p + k;
                s[k] = col[pk < p1 ? pk : last].x;   // clamp: dup line, L1-hit
            }
            unsigned u[8];
#pragma unroll
            for (int k = 0; k < 8; k++)
                u[k] = *(const unsigned*)(y + (size_t)s[k] * 64 + 2 * f);
            float sx = 0.f, sy = 0.f;
#pragma unroll
            for (int k = 0; k < 8; k++) {
                bool ok = (p + k) < p1;
                sx += ok ? bpk_lo(u[k]) : 0.f;
                sy += ok ? bpk_hi(u[k]) : 0.f;
            }
            ax += sx; ay += sy;
        }
        // + agg_e @ W2.T
        const float4* aev = (const float4*)(agge + (size_t)nn * 16);
#pragma unroll
        for (int q = 0; q < 4; q++) {
            float4 a4 = aev[q];
            int m0 = q * 4;
            ax += a4.x * W2t[(m0 + 0) * 64 + 2 * f] + a4.y * W2t[(m0 + 1) * 64 + 2 * f]
                + a4.z * W2t[(m0 + 2) * 64 + 2 * f] + a4.w * W2t[(m0 + 3) * 64 + 2 * f];
            ay += a4.x * W2t[(m0 + 0) * 64 + 2 * f + 1] + a4.y * W2t[(m0 + 1) * 64 + 2 * f + 1]
                + a4.z * W2t[(m0 + 2) * 64 + 2 * f + 1] + a4.w * W2t[(m0 + 3) * 64 + 2 * f + 1];
        }
        if (valid) {
            unsigned o = ((unsigned)f2b(ax)) | (((unsigned)f2b(ay)) << 16);
            *(unsigned*)(xb + (size_t)n * 64 + 2 * f) = o;
        }
    }
}

// ---------------- head: sigmoid(lin2(lin1(fp))) — all f32 ----------------
__global__ __launch_bounds__(256) void k_head(
    const float* __restrict__ fp, const float* __restrict__ l1w, const float* __restrict__ l1b,
    const float* __restrict__ l2w, const float* __restrict__ l2b, float* __restrict__ out, int G)
{
    const int wid = threadIdx.x >> 6, lane = threadIdx.x & 63;
    int g = blockIdx.x * 4 + wid;
    if (g >= G) return;
    int j = lane < 50 ? lane : 49;
    float h = 0.f;
    const float4* fv = (const float4*)(fp + (size_t)g * 512);
    const float4* wv = (const float4*)(l1w + (size_t)j * 512);
    for (int q = 0; q < 128; q++) {
        float4 w = wv[q], f = fv[q];
        h += w.x * f.x + w.y * f.y + w.z * f.z + w.w * f.w;
    }
    h += l1b[j];
    float val = (lane < 50) ? h * l2w[lane] : 0.f;
#pragma unroll
    for (int off = 1; off < 64; off <<= 1) val += __shfl_xor(val, off, 64);
    if (lane == 0) {
        float o = val + l2b[0];
        out[g] = 1.f / (1.f + __expf(-o));
    }
}

extern "C" void kernel_launch(void* const* d_in, const int* in_sizes, int n_in,
                              void* d_out, int out_size, void* d_ws, size_t ws_size,
                              hipStream_t stream)
{
    const float* x    = (const float*)d_in[0];
    const float* ea   = (const float*)d_in[1];
    const float* Wiw  = (const float*)d_in[2];
    const float* Wib  = (const float*)d_in[3];
    const float* Wow  = (const float*)d_in[4];
    const float* Wob  = (const float*)d_in[5];
    const float* l1w  = (const float*)d_in[6];
    const float* l1b  = (const float*)d_in[7];
    const float* l2w  = (const float*)d_in[8];
    const float* l2b  = (const float*)d_in[9];
    const int* ei     = (const int*)d_in[10];
    const int* batch  = (const int*)d_in[11];
    float* out = (float*)d_out;

    const int N = in_sizes[0] / 64;
    const int E = in_sizes[10] / 2;
    const int G = 16384;
    const int* src = ei;
    const int* dst = ei + E;

    size_t o = 0;
    auto give = [&](size_t bytes) {
        char* p = (char*)d_ws + o;
        o += (bytes + 255) & ~(size_t)255;
        return (void*)p;
    };
    u16*   x16     = (u16*)  give((size_t)N * 64 * 2);   // bf16 cast of input x
    u16*   xb      = (u16*)  give((size_t)N * 64 * 2);   // conv output (bf16)
    u16*   y       = (u16*)  give((size_t)N * 64 * 2);   // x @ W1.T  (bf16)
    float* agge    = (float*)give((size_t)N * 16 * 4);
    float* fp      = (float*)give((size_t)G * 512 * 4);
    int*   rp      = (int*)  give((size_t)(N + 1) * 4);
    int*   cursor  = (int*)  give((size_t)N * 4);
    int2*  col     = (int2*) give((size_t)E * 8);        // packed (src, eid)
    int*   bsum    = (int*)  give(4096);
    int*   gptr    = (int*)  give((size_t)(G + 1) * 4);

    // CSR build (inputs identical each call so result identical each launch)
    hipMemsetAsync(rp, 0, (size_t)(N + 1) * 4, stream);
    k_deg<<<(E + 255) / 256, 256, 0, stream>>>(dst, rp, E);
    int nb = (N + SCAN_CH - 1) / SCAN_CH;       // 245 for N=500000 (must be <= 256)
    k_scanA<<<nb, SCAN_T, 0, stream>>>(rp, bsum, N);
    k_scanB<<<1, SCAN_T, 0, stream>>>(bsum, nb);
    k_scanC<<<(N + 256) / 256, 256, 0, stream>>>(bsum, rp, cursor, N, E);
    k_fill<<<(E + 255) / 256, 256, 0, stream>>>(src, dst, cursor, col, E);
    k_gptr<<<(G + 256) / 256, 256, 0, stream>>>(batch, gptr, N, G);
    k_agge<<<(N * 16 + 255) / 256, 256, 0, stream>>>(ea, rp, col, agge, N);

    // cast input x -> bf16
    k_cast<<<(N * 64 / 8 + 255) / 256, 256, 0, stream>>>(x, x16, N * 64 / 8);

    // pass 0 on input x (writes fp)
    k_pass<<<2048, 256, 0, stream>>>(x16, Wow, Wob, gptr, fp, G, 1);
    const u16* xc = x16;
    for (int d = 0; d < 4; d++) {
        k_gemm<<<1024, 256, 0, stream>>>(xc, Wiw, y, N);
        k_gath<<<2048, 256, 0, stream>>>(y, agge, Wiw, Wib, rp, col, xb, N);
        xc = xb;
        k_pass<<<2048, 256, 0, stream>>>(xc, Wow, Wob, gptr, fp, G, 0);
    }
    k_head<<<G / 4, 256, 0, stream>>>(fp, l1w, l1b, l2w, l2b, out, G);
}

// Round 5
// 2766.937 us; speedup vs baseline: 1.2353x; 1.0522x over previous
//
#include <hip/hip_runtime.h>

typedef unsigned short u16;
typedef short bfx8 __attribute__((ext_vector_type(8)));
typedef float fx4 __attribute__((ext_vector_type(4)));

__device__ __forceinline__ float b2f(u16 u) {
    union { unsigned u; float f; } c; c.u = ((unsigned)u) << 16; return c.f;
}
__device__ __forceinline__ u16 f2b(float f) {
    union { float f; unsigned u; } c; c.f = f;
    unsigned x = c.u;
    unsigned r = x + 0x7FFFu + ((x >> 16) & 1u);
    return (u16)(r >> 16);
}
__device__ __forceinline__ float bpk_lo(unsigned p) {
    union { unsigned u; float f; } c; c.u = p << 16; return c.f;
}
__device__ __forceinline__ float bpk_hi(unsigned p) {
    union { unsigned u; float f; } c; c.u = p & 0xFFFF0000u; return c.f;
}
// pack two f32 into one reg of 2x bf16 (RNE) -- single VALU instr
__device__ __forceinline__ unsigned cvtpk(float lo, float hi) {
    unsigned r;
    asm("v_cvt_pk_bf16_f32 %0, %1, %2" : "=v"(r) : "v"(lo), "v"(hi));
    return r;
}

// ---------------- f32 -> bf16 cast (8 elems/thread) ----------------
__global__ void k_cast(const float* __restrict__ xf, u16* __restrict__ xb, int n8) {
    int t = blockIdx.x * 256 + threadIdx.x;
    if (t >= n8) return;
    const float4* p = (const float4*)xf;
    float4 a = p[t * 2], b = p[t * 2 + 1];
    u16 o[8];
    o[0] = f2b(a.x); o[1] = f2b(a.y); o[2] = f2b(a.z); o[3] = f2b(a.w);
    o[4] = f2b(b.x); o[5] = f2b(b.y); o[6] = f2b(b.z); o[7] = f2b(b.w);
    ((uint4*)xb)[t] = *(uint4*)o;
}

// ---------------- CSR build ----------------

__global__ void k_deg(const int* __restrict__ dst, int* __restrict__ rp, int E) {
    int e = blockIdx.x * 256 + threadIdx.x;
    if (e < E) atomicAdd(&rp[dst[e]], 1);
}

#define SCAN_T 256
#define SCAN_I 8
#define SCAN_CH 2048

__global__ void k_scanA(int* __restrict__ rp, int* __restrict__ bsum, int N) {
    __shared__ int s[SCAN_T];
    int base = blockIdx.x * SCAN_CH + threadIdx.x * SCAN_I;
    int v[SCAN_I]; int tot = 0;
    for (int i = 0; i < SCAN_I; i++) {
        int idx = base + i;
        int x = (idx < N) ? rp[idx] : 0;
        v[i] = tot; tot += x;
    }
    s[threadIdx.x] = tot; __syncthreads();
    for (int off = 1; off < SCAN_T; off <<= 1) {
        int t = (threadIdx.x >= off) ? s[threadIdx.x - off] : 0;
        __syncthreads();
        s[threadIdx.x] += t;
        __syncthreads();
    }
    int excl = (threadIdx.x == 0) ? 0 : s[threadIdx.x - 1];
    if (threadIdx.x == SCAN_T - 1) bsum[blockIdx.x] = s[SCAN_T - 1];
    for (int i = 0; i < SCAN_I; i++) {
        int idx = base + i;
        if (idx < N) rp[idx] = excl + v[i];
    }
}

__global__ void k_scanB(int* __restrict__ bsum, int nb) {
    __shared__ int s[SCAN_T];
    int t = threadIdx.x;
    s[t] = (t < nb) ? bsum[t] : 0; __syncthreads();
    for (int off = 1; off < SCAN_T; off <<= 1) {
        int v = (t >= off) ? s[t - off] : 0;
        __syncthreads();
        s[t] += v;
        __syncthreads();
    }
    if (t < nb) bsum[t] = (t == 0) ? 0 : s[t - 1];
}

__global__ void k_scanC(const int* __restrict__ bsum, int* __restrict__ rp,
                        int* __restrict__ cursor, int N, int E) {
    int i = blockIdx.x * 256 + threadIdx.x;
    if (i < N) {
        int v = rp[i] + bsum[i >> 11];
        rp[i] = v; cursor[i] = v;
    } else if (i == N) {
        rp[N] = E;
    }
}

// v4: 4 edges/thread, phase-separated (loads -> 4 independent atomics -> stores).
// One edge/thread left exactly ONE long-latency atomic-with-return in flight per
// wave-slot (VALUBusy 0.3%, pure vmcnt stall). 4 independent atomics quadruple MLP
// at identical traffic. Slot order within a dst bucket is arbitrary -- sum is
// commutative, any permutation is valid.
__global__ void k_fill(const int* __restrict__ src, const int* __restrict__ dst,
                       int* __restrict__ cursor, int2* __restrict__ col, int E) {
    int e0 = (blockIdx.x * 256 + threadIdx.x) * 4;
    if (e0 >= E) return;
    int ne = E - e0; if (ne > 4) ne = 4;
    int d[4], s[4], p[4];
#pragma unroll
    for (int k = 0; k < 4; k++) if (k < ne) { d[k] = dst[e0 + k]; s[k] = src[e0 + k]; }
#pragma unroll
    for (int k = 0; k < 4; k++) if (k < ne) p[k] = atomicAdd(&cursor[d[k]], 1);
#pragma unroll
    for (int k = 0; k < 4; k++) if (k < ne) col[p[k]] = make_int2(s[k], e0 + k);
}

__global__ void k_gptr(const int* __restrict__ batch, int* __restrict__ gptr, int N, int G) {
    int g = blockIdx.x * 256 + threadIdx.x;
    if (g > G) return;
    int lo = 0, hi = N;
    while (lo < hi) { int mid = (lo + hi) >> 1; if (batch[mid] < g) lo = mid + 1; else hi = mid; }
    gptr[g] = lo;
}

// agg_e[n][m] = sum of edge_attr (f32) over in-edges of n (constant across convs)
// chunk-8 batched eid loads then 8 independent row loads -> 8 lines in flight
__global__ void k_agge(const float* __restrict__ ea, const int* __restrict__ rp,
                       const int2* __restrict__ col, float* __restrict__ agge, int N) {
    int t = blockIdx.x * 256 + threadIdx.x;
    int n = t >> 4, m = t & 15;
    if (n >= N) return;
    float v = 0.f;
    int p0 = rp[n], p1 = rp[n + 1];
    int last = p1 - 1;
    for (int p = p0; p < p1; p += 8) {
        int e[8];
#pragma unroll
        for (int k = 0; k < 8; k++) {
            int pk = p + k;
            e[k] = col[pk < p1 ? pk : last].y;   // clamp: dup line, L1-hit
        }
        float w[8];
#pragma unroll
        for (int k = 0; k < 8; k++) w[k] = ea[(size_t)e[k] * 16 + m];
#pragma unroll
        for (int k = 0; k < 8; k++) v += (p + k < p1) ? w[k] : 0.f;
    }
    agge[(size_t)n * 16 + m] = v;
}

// ---------------- fused softmax + segment-sum pool (wave-autonomous, single MFMA+exp pass) ------
// v4: each wave owns a graph (no block barriers in the main loop -> latency hiding
// across 4 waves/block x 2 blocks/CU). Per 32-node tile: ONE MFMA+exp pass; exp(z)
// is kept in registers packed as bf16 (v_cvt_pk_bf16_f32; bf16 = truncated f32 so
// no overflow, 2^-9 rel err << existing bf16-input noise). Denominators via 16-lane
// shfl reduce; phase 2 unpacks and accumulates exp*rinv into fpacc registers.
__global__ __launch_bounds__(256, 2) void k_pass(
    const u16* __restrict__ x, const float* __restrict__ Wow, const float* __restrict__ Wob,
    const int* __restrict__ gptr, float* __restrict__ fp, int G, int writeMode)
{
    __shared__ u16 Wsw[64 * 64 * 8];   // [64 frags][64 lanes][8 bf16] = 64 KB
    __shared__ float biasL[512];
    for (int s = threadIdx.x; s < 4096; s += 256) {
        int frag = s >> 6, lane = s & 63;
        int ft = frag >> 1, kt = frag & 1;
        int f = ft * 16 + (lane & 15);
        int k = kt * 32 + ((lane >> 4) & 3) * 8;
        const float* wp = Wow + f * 64 + k;      // B[k][f] = W_out[f][k], 8 consecutive k
        u16 o[8];
#pragma unroll
        for (int i = 0; i < 8; i++) o[i] = f2b(wp[i]);
        ((uint4*)Wsw)[s] = *(uint4*)o;
    }
    for (int s = threadIdx.x; s < 512; s += 256) biasL[s] = Wob[s];
    __syncthreads();
    const int wid = threadIdx.x >> 6, lane = threadIdx.x & 63;
    const int quad = lane >> 4, col = lane & 15;

    for (int g = blockIdx.x * 4 + wid; g < G; g += gridDim.x * 4) {
        const int gs = gptr[g], ge = gptr[g + 1];
        const int cnt = ge - gs;
        float fpacc[32];
#pragma unroll
        for (int t = 0; t < 32; t++) fpacc[t] = 0.f;

        uint4 p0, p1, p2, p3;
        if (gs < ge) {   // preload first tile (rows clamped to gs; garbage killed by rinv=0)
            int n0 = gs + col, n1 = n0 + 16;
            const uint4* r0 = (const uint4*)(x + (size_t)((n0 < ge) ? n0 : gs) * 64);
            const uint4* r1 = (const uint4*)(x + (size_t)((n1 < ge) ? n1 : gs) * 64);
            p0 = r0[quad]; p1 = r0[quad + 4]; p2 = r1[quad]; p3 = r1[quad + 4];
        }

        for (int base = gs; base < ge; base += 32) {
            bfx8 a0 = *(bfx8*)&p0, a1 = *(bfx8*)&p1, a2 = *(bfx8*)&p2, a3 = *(bfx8*)&p3;
            if (base + 32 < ge) {   // prefetch next tile under this tile's compute
                int b = base + 32;
                int n0 = b + col, n1 = n0 + 16;
                const uint4* r0 = (const uint4*)(x + (size_t)((n0 < ge) ? n0 : gs) * 64);
                const uint4* r1 = (const uint4*)(x + (size_t)((n1 < ge) ? n1 : gs) * 64);
                p0 = r0[quad]; p1 = r0[quad + 4]; p2 = r1[quad]; p3 = r1[quad + 4];
            }

            // phase 1: z = x@W.T + b, e = exp(z) -> packed bf16 regs, s += e
            unsigned epk[128];
            float s0[4] = {0.f, 0.f, 0.f, 0.f}, s1[4] = {0.f, 0.f, 0.f, 0.f};
#pragma unroll
            for (int ft = 0; ft < 32; ft++) {
                float b = biasL[ft * 16 + col];
                bfx8 b0 = *(bfx8*)(Wsw + ((ft * 2 + 0) * 64 + lane) * 8);
                bfx8 b1 = *(bfx8*)(Wsw + ((ft * 2 + 1) * 64 + lane) * 8);
                fx4 acc0 = {b, b, b, b}, acc1 = {b, b, b, b};
                acc0 = __builtin_amdgcn_mfma_f32_16x16x32_bf16(a0, b0, acc0, 0, 0, 0);
                acc0 = __builtin_amdgcn_mfma_f32_16x16x32_bf16(a1, b1, acc0, 0, 0, 0);
                acc1 = __builtin_amdgcn_mfma_f32_16x16x32_bf16(a2, b0, acc1, 0, 0, 0);
                acc1 = __builtin_amdgcn_mfma_f32_16x16x32_bf16(a3, b1, acc1, 0, 0, 0);
                float e00 = __expf(acc0[0]), e01 = __expf(acc0[1]);
                float e02 = __expf(acc0[2]), e03 = __expf(acc0[3]);
                float e10 = __expf(acc1[0]), e11 = __expf(acc1[1]);
                float e12 = __expf(acc1[2]), e13 = __expf(acc1[3]);
                s0[0] += e00; s0[1] += e01; s0[2] += e02; s0[3] += e03;
                s1[0] += e10; s1[1] += e11; s1[2] += e12; s1[3] += e13;
                epk[ft * 4 + 0] = cvtpk(e00, e01);
                epk[ft * 4 + 1] = cvtpk(e02, e03);
                epk[ft * 4 + 2] = cvtpk(e10, e11);
                epk[ft * 4 + 3] = cvtpk(e12, e13);
            }
            // denominators: reduce over the 16 col-lanes (each holds 32 of 512 feats)
            float rinv0[4], rinv1[4];
#pragma unroll
            for (int r = 0; r < 4; r++) {
                float t0 = s0[r], t1 = s1[r];
#pragma unroll
                for (int off = 1; off < 16; off <<= 1) {
                    t0 += __shfl_xor(t0, off, 64);
                    t1 += __shfl_xor(t1, off, 64);
                }
                int row0 = base - gs + quad * 4 + r;
                rinv0[r] = (row0 < cnt) ? __builtin_amdgcn_rcpf(t0) : 0.f;
                rinv1[r] = (row0 + 16 < cnt) ? __builtin_amdgcn_rcpf(t1) : 0.f;
            }
            // phase 2: fpacc[ft] += sum_rows e * rinv   (unpack bf16, 8 FMA/ft)
#pragma unroll
            for (int ft = 0; ft < 32; ft++) {
                float add =
                      bpk_lo(epk[ft * 4 + 0]) * rinv0[0] + bpk_hi(epk[ft * 4 + 0]) * rinv0[1]
                    + bpk_lo(epk[ft * 4 + 1]) * rinv0[2] + bpk_hi(epk[ft * 4 + 1]) * rinv0[3]
                    + bpk_lo(epk[ft * 4 + 2]) * rinv1[0] + bpk_hi(epk[ft * 4 + 2]) * rinv1[1]
                    + bpk_lo(epk[ft * 4 + 3]) * rinv1[2] + bpk_hi(epk[ft * 4 + 3]) * rinv1[3];
                fpacc[ft] += add;
            }
        }
        // cross-quad reduce + write
#pragma unroll
        for (int ft = 0; ft < 32; ft++) {
            float v = fpacc[ft];
            v += __shfl_xor(v, 16, 64);
            v += __shfl_xor(v, 32, 64);
            if (lane < 16) {
                float* dp = fp + (size_t)g * 512 + ft * 16 + col;
                if (writeMode) *dp = v; else *dp += v;
            }
        }
    }
}

// ---------------- conv part 1: y = x @ W1.T (MFMA, N x 64 x 64) ----------------
__global__ __launch_bounds__(256) void k_gemm(
    const u16* __restrict__ x, const float* __restrict__ Wiw, u16* __restrict__ y, int N)
{
    __shared__ u16 Wsw[8 * 64 * 8];
    for (int s = threadIdx.x; s < 512; s += 256) {
        int frag = s >> 6, lane = s & 63;
        int ft = frag >> 1, kt = frag & 1;
        int f = ft * 16 + (lane & 15);
        int k = kt * 32 + ((lane >> 4) & 3) * 8;
        const float* wp = Wiw + f * 80 + k;      // W1[f][k] = W_in_w[f*80 + k]
        u16 o[8];
#pragma unroll
        for (int i = 0; i < 8; i++) o[i] = f2b(wp[i]);
        ((uint4*)Wsw)[s] = *(uint4*)o;
    }
    __syncthreads();
    const int wid = threadIdx.x >> 6, lane = threadIdx.x & 63;
    const int quad = lane >> 4, col = lane & 15;
    int ntile = N >> 4;
    for (int t = blockIdx.x * 4 + wid; t < ntile; t += gridDim.x * 4) {
        const uint4* rowp = (const uint4*)(x + (size_t)(t * 16 + col) * 64);
        uint4 a0u = rowp[quad], a1u = rowp[quad + 4];
        bfx8 a0 = *(bfx8*)&a0u, a1 = *(bfx8*)&a1u;
#pragma unroll
        for (int ft = 0; ft < 4; ft++) {
            fx4 acc = {0.f, 0.f, 0.f, 0.f};
            bfx8 b0 = *(bfx8*)(Wsw + ((ft * 2 + 0) * 64 + lane) * 8);
            bfx8 b1 = *(bfx8*)(Wsw + ((ft * 2 + 1) * 64 + lane) * 8);
            acc = __builtin_amdgcn_mfma_f32_16x16x32_bf16(a0, b0, acc, 0, 0, 0);
            acc = __builtin_amdgcn_mfma_f32_16x16x32_bf16(a1, b1, acc, 0, 0, 0);
#pragma unroll
            for (int r = 0; r < 4; r++)
                y[(size_t)(t * 16 + quad * 4 + r) * 64 + ft * 16 + col] = f2b(acc[r]);
        }
    }
}

// ---------------- conv part 2: x_out[n] = y[n] + sum_{e->n} y[src] + agg_e[n]@W2.T + b --------
// 2 nodes/wave (32 lanes x bf16-pair each -> dword row loads) + chunk-8 batched
// index / row loads => up to 16 cache lines in flight per wave.
__global__ __launch_bounds__(256) void k_gath(
    const u16* __restrict__ y, const float* __restrict__ agge,
    const float* __restrict__ Wiw, const float* __restrict__ Wib,
    const int* __restrict__ rp, const int2* __restrict__ col,
    u16* __restrict__ xb, int N)
{
    __shared__ float W2t[16 * 64];
    __shared__ float bias[64];
    for (int s = threadIdx.x; s < 1024; s += 256) {
        int m = s >> 6, j = s & 63;
        W2t[s] = Wiw[j * 80 + 64 + m];
    }
    if (threadIdx.x < 64) bias[threadIdx.x] = Wib[threadIdx.x];
    __syncthreads();
    const int wid = threadIdx.x >> 6, lane = threadIdx.x & 63;
    const int half = lane >> 5, f = lane & 31;     // this lane owns features 2f, 2f+1
    const int P = (N + 1) >> 1;                    // node pairs
    const int nw = gridDim.x * 4;
    for (int i = blockIdx.x * 4 + wid; i < P; i += nw) {
        int n = i * 2 + half;
        bool valid = n < N;
        int nn = valid ? n : (N - 1);
        // self loop + bias
        unsigned su = *(const unsigned*)(y + (size_t)nn * 64 + 2 * f);
        float ax = bpk_lo(su) + bias[2 * f];
        float ay = bpk_hi(su) + bias[2 * f + 1];
        int p0 = rp[nn], p1 = rp[nn + 1];
        int last = p1 - 1;
        for (int p = p0; p < p1; p += 8) {
            int s[8];
#pragma unroll
            for (int k = 0; k < 8; k++) {
                int pk = p + k;
                s[k] = col[pk < p1 ? pk : last].x;   // clamp: dup line, L1-hit
            }
            unsigned u[8];
#pragma unroll
            for (int k = 0; k < 8; k++)
                u[k] = *(const unsigned*)(y + (size_t)s[k] * 64 + 2 * f);
            float sx = 0.f, sy = 0.f;
#pragma unroll
            for (int k = 0; k < 8; k++) {
                bool ok = (p + k) < p1;
                sx += ok ? bpk_lo(u[k]) : 0.f;
                sy += ok ? bpk_hi(u[k]) : 0.f;
            }
            ax += sx; ay += sy;
        }
        // + agg_e @ W2.T
        const float4* aev = (const float4*)(agge + (size_t)nn * 16);
#pragma unroll
        for (int q = 0; q < 4; q++) {
            float4 a4 = aev[q];
            int m0 = q * 4;
            ax += a4.x * W2t[(m0 + 0) * 64 + 2 * f] + a4.y * W2t[(m0 + 1) * 64 + 2 * f]
                + a4.z * W2t[(m0 + 2) * 64 + 2 * f] + a4.w * W2t[(m0 + 3) * 64 + 2 * f];
            ay += a4.x * W2t[(m0 + 0) * 64 + 2 * f + 1] + a4.y * W2t[(m0 + 1) * 64 + 2 * f + 1]
                + a4.z * W2t[(m0 + 2) * 64 + 2 * f + 1] + a4.w * W2t[(m0 + 3) * 64 + 2 * f + 1];
        }
        if (valid) {
            unsigned o = ((unsigned)f2b(ax)) | (((unsigned)f2b(ay)) << 16);
            *(unsigned*)(xb + (size_t)n * 64 + 2 * f) = o;
        }
    }
}

// ---------------- head: sigmoid(lin2(lin1(fp))) — all f32 ----------------
__global__ __launch_bounds__(256) void k_head(
    const float* __restrict__ fp, const float* __restrict__ l1w, const float* __restrict__ l1b,
    const float* __restrict__ l2w, const float* __restrict__ l2b, float* __restrict__ out, int G)
{
    const int wid = threadIdx.x >> 6, lane = threadIdx.x & 63;
    int g = blockIdx.x * 4 + wid;
    if (g >= G) return;
    int j = lane < 50 ? lane : 49;
    float h = 0.f;
    const float4* fv = (const float4*)(fp + (size_t)g * 512);
    const float4* wv = (const float4*)(l1w + (size_t)j * 512);
    for (int q = 0; q < 128; q++) {
        float4 w = wv[q], f = fv[q];
        h += w.x * f.x + w.y * f.y + w.z * f.z + w.w * f.w;
    }
    h += l1b[j];
    float val = (lane < 50) ? h * l2w[lane] : 0.f;
#pragma unroll
    for (int off = 1; off < 64; off <<= 1) val += __shfl_xor(val, off, 64);
    if (lane == 0) {
        float o = val + l2b[0];
        out[g] = 1.f / (1.f + __expf(-o));
    }
}

extern "C" void kernel_launch(void* const* d_in, const int* in_sizes, int n_in,
                              void* d_out, int out_size, void* d_ws, size_t ws_size,
                              hipStream_t stream)
{
    const float* x    = (const float*)d_in[0];
    const float* ea   = (const float*)d_in[1];
    const float* Wiw  = (const float*)d_in[2];
    const float* Wib  = (const float*)d_in[3];
    const float* Wow  = (const float*)d_in[4];
    const float* Wob  = (const float*)d_in[5];
    const float* l1w  = (const float*)d_in[6];
    const float* l1b  = (const float*)d_in[7];
    const float* l2w  = (const float*)d_in[8];
    const float* l2b  = (const float*)d_in[9];
    const int* ei     = (const int*)d_in[10];
    const int* batch  = (const int*)d_in[11];
    float* out = (float*)d_out;

    const int N = in_sizes[0] / 64;
    const int E = in_sizes[10] / 2;
    const int G = 16384;
    const int* src = ei;
    const int* dst = ei + E;

    size_t o = 0;
    auto give = [&](size_t bytes) {
        char* p = (char*)d_ws + o;
        o += (bytes + 255) & ~(size_t)255;
        return (void*)p;
    };
    u16*   x16     = (u16*)  give((size_t)N * 64 * 2);   // bf16 cast of input x
    u16*   xb      = (u16*)  give((size_t)N * 64 * 2);   // conv output (bf16)
    u16*   y       = (u16*)  give((size_t)N * 64 * 2);   // x @ W1.T  (bf16)
    float* agge    = (float*)give((size_t)N * 16 * 4);
    float* fp      = (float*)give((size_t)G * 512 * 4);
    int*   rp      = (int*)  give((size_t)(N + 1) * 4);
    int*   cursor  = (int*)  give((size_t)N * 4);
    int2*  col     = (int2*) give((size_t)E * 8);        // packed (src, eid)
    int*   bsum    = (int*)  give(4096);
    int*   gptr    = (int*)  give((size_t)(G + 1) * 4);

    // CSR build (inputs identical each call so result identical each launch)
    hipMemsetAsync(rp, 0, (size_t)(N + 1) * 4, stream);
    k_deg<<<(E + 255) / 256, 256, 0, stream>>>(dst, rp, E);
    int nb = (N + SCAN_CH - 1) / SCAN_CH;       // 245 for N=500000 (must be <= 256)
    k_scanA<<<nb, SCAN_T, 0, stream>>>(rp, bsum, N);
    k_scanB<<<1, SCAN_T, 0, stream>>>(bsum, nb);
    k_scanC<<<(N + 256) / 256, 256, 0, stream>>>(bsum, rp, cursor, N, E);
    k_fill<<<(E / 4 + 255) / 256, 256, 0, stream>>>(src, dst, cursor, col, E);
    k_gptr<<<(G + 256) / 256, 256, 0, stream>>>(batch, gptr, N, G);
    k_agge<<<(N * 16 + 255) / 256, 256, 0, stream>>>(ea, rp, col, agge, N);

    // cast input x -> bf16
    k_cast<<<(N * 64 / 8 + 255) / 256, 256, 0, stream>>>(x, x16, N * 64 / 8);

    // pass 0 on input x (writes fp)
    k_pass<<<2048, 256, 0, stream>>>(x16, Wow, Wob, gptr, fp, G, 1);
    const u16* xc = x16;
    for (int d = 0; d < 4; d++) {
        k_gemm<<<1024, 256, 0, stream>>>(xc, Wiw, y, N);
        k_gath<<<2048, 256, 0, stream>>>(y, agge, Wiw, Wib, rp, col, xb, N);
        xc = xb;
        k_pass<<<2048, 256, 0, stream>>>(xc, Wow, Wob, gptr, fp, G, 0);
    }
    k_head<<<G / 4, 256, 0, stream>>>(fp, l1w, l1b, l2w, l2b, out, G);
}